// Round 1
// baseline (1769.319 us; speedup 1.0000x reference)
//
#include <hip/hip_runtime.h>
#include <hip/hip_bf16.h>

#define BATCH 2
#define SEQ   1024
#define DM    768
#define NH    12
#define DK    64

// ---------------- ws layout (float offsets) ----------------
// qs    [B,S,768]        @ 0          (pre-scaled by 1/64)
// ks    [B,S,768]        @ 1572864
// vs    [B,S,768]        @ 3145728
// attn  [B,S,768]        @ 4718592    (wv + w_rel, pre-Wo)
// scores[B,H,S,S]        @ 6291456    (25165824 floats)
#define OFF_QS    0
#define OFF_KS    1572864
#define OFF_VS    3145728
#define OFF_ATTN  4718592
#define OFF_SC    6291456

// ============ generic tiled fp32 GEMM: C = alpha*(X[2048,768] @ W[768,768] + b) ============
// BM=BN=64, BK=16, 256 threads, 4x4 per thread
__global__ __launch_bounds__(256) void gemm_bias_kernel(
    const float* __restrict__ X, const float* __restrict__ W,
    const float* __restrict__ bias, float* __restrict__ C, float alpha)
{
    __shared__ float As[16][65];  // As[k][m]
    __shared__ float Bs[16][65];  // Bs[k][n]
    const int bm = blockIdx.x, bn = blockIdx.y;
    const int tid = threadIdx.x;
    const int tx = tid & 15, ty = tid >> 4;
    float acc[4][4] = {};
    for (int kt = 0; kt < DM; kt += 16) {
        __syncthreads();
#pragma unroll
        for (int l = 0; l < 4; ++l) {
            int idx = tid + l * 256;
            int m = idx >> 4, kk = idx & 15;
            As[kk][m] = X[(bm * 64 + m) * DM + kt + kk];
        }
#pragma unroll
        for (int l = 0; l < 4; ++l) {
            int idx = tid + l * 256;
            int kk = idx >> 6, n = idx & 63;
            Bs[kk][n] = W[(kt + kk) * DM + bn * 64 + n];
        }
        __syncthreads();
#pragma unroll
        for (int kk = 0; kk < 16; ++kk) {
            float a[4], bb[4];
#pragma unroll
            for (int i = 0; i < 4; ++i) a[i] = As[kk][ty * 4 + i];
#pragma unroll
            for (int j = 0; j < 4; ++j) bb[j] = Bs[kk][tx * 4 + j];
#pragma unroll
            for (int i = 0; i < 4; ++i)
#pragma unroll
                for (int j = 0; j < 4; ++j) acc[i][j] += a[i] * bb[j];
        }
    }
#pragma unroll
    for (int i = 0; i < 4; ++i) {
        int row = bm * 64 + ty * 4 + i;
#pragma unroll
        for (int j = 0; j < 4; ++j) {
            int col = bn * 64 + tx * 4 + j;
            C[row * DM + col] = alpha * (acc[i][j] + bias[col]);
        }
    }
}

// ============ qk logits: scores[b,h,q,k] = qs[b,q,h,:] . ks[b,k,h,:] ============
// grid (kt=16, qt=16, bh=24), 64x64 tile
__global__ __launch_bounds__(256) void qk_kernel(
    const float* __restrict__ qs, const float* __restrict__ ks,
    float* __restrict__ scores)
{
    const int kt = blockIdx.x, qt = blockIdx.y, bh = blockIdx.z;
    const int b = bh / NH, h = bh % NH;
    __shared__ float Qs[64][65];
    __shared__ float Ks[64][65];
    const int tid = threadIdx.x;
#pragma unroll
    for (int l = 0; l < 16; ++l) {
        int idx = tid + l * 256;
        int m = idx >> 6, d = idx & 63;
        Qs[m][d] = qs[(b * SEQ + qt * 64 + m) * DM + h * 64 + d];
        Ks[m][d] = ks[(b * SEQ + kt * 64 + m) * DM + h * 64 + d];
    }
    __syncthreads();
    const int tx = tid & 15, ty = tid >> 4;
    float acc[4][4] = {};
#pragma unroll 8
    for (int d = 0; d < 64; ++d) {
        float a[4], bb[4];
#pragma unroll
        for (int i = 0; i < 4; ++i) a[i] = Qs[ty * 4 + i][d];
#pragma unroll
        for (int j = 0; j < 4; ++j) bb[j] = Ks[tx * 4 + j][d];
#pragma unroll
        for (int i = 0; i < 4; ++i)
#pragma unroll
            for (int j = 0; j < 4; ++j) acc[i][j] += a[i] * bb[j];
    }
#pragma unroll
    for (int i = 0; i < 4; ++i) {
        int q = qt * 64 + ty * 4 + i;
#pragma unroll
        for (int j = 0; j < 4; ++j) {
            int k = kt * 64 + tx * 4 + j;
            scores[((size_t)bh * SEQ + q) * SEQ + k] = acc[i][j];
        }
    }
}

// ============ rel-k logits: scores[b,h,q,k] += qs[b,q,h,:] . relation_k[b,q,k,:] ============
// grid (kc=4, q=1024, b=2); each block does 256 keys, all 12 heads
__global__ __launch_bounds__(256) void relk_kernel(
    const float* __restrict__ qs, const float* __restrict__ rk,
    float* __restrict__ scores)
{
    const int kc = blockIdx.x, q = blockIdx.y, b = blockIdx.z;
    __shared__ float qv[DM];
    __shared__ float Rs[64][65];
    const int tid = threadIdx.x;
    if (tid < 192) {
        float4 t = *(const float4*)&qs[(b * SEQ + q) * DM + tid * 4];
        *(float4*)&qv[tid * 4] = t;
    }
    const int k = tid & 63;
    const int hb = tid >> 6;  // 0..3 -> heads hb, hb+4, hb+8
    const size_t rbase = ((size_t)(b * SEQ + q)) * SEQ * DK;
    for (int sub = 0; sub < 4; ++sub) {
        const int k0 = kc * 256 + sub * 64;
        __syncthreads();
#pragma unroll
        for (int l = 0; l < 16; ++l) {
            int idx = tid + l * 256;
            int kk = idx >> 6, d = idx & 63;
            Rs[kk][d] = rk[rbase + (size_t)(k0 + kk) * DK + d];
        }
        __syncthreads();
        float a0 = 0.f, a1 = 0.f, a2 = 0.f;
#pragma unroll 8
        for (int d = 0; d < 64; ++d) {
            float r = Rs[k][d];
            a0 += r * qv[hb * 64 + d];
            a1 += r * qv[(hb + 4) * 64 + d];
            a2 += r * qv[(hb + 8) * 64 + d];
        }
        size_t s0 = ((size_t)(b * NH + hb) * SEQ + q) * SEQ + k0 + k;
        scores[s0] += a0;
        scores[s0 + (size_t)4 * SEQ * SEQ] += a1;
        scores[s0 + (size_t)8 * SEQ * SEQ] += a2;
    }
}

// ============ softmax over last dim (1024), in place ============
__global__ __launch_bounds__(256) void softmax_kernel(float* __restrict__ scores)
{
    const int row = blockIdx.x;
    float* p = scores + (size_t)row * SEQ;
    const int tid = threadIdx.x;
    float4 x = *(float4*)&p[tid * 4];
    float m = fmaxf(fmaxf(x.x, x.y), fmaxf(x.z, x.w));
#pragma unroll
    for (int off = 32; off > 0; off >>= 1) m = fmaxf(m, __shfl_xor(m, off));
    __shared__ float redm[4], reds[4];
    if ((tid & 63) == 0) redm[tid >> 6] = m;
    __syncthreads();
    m = fmaxf(fmaxf(redm[0], redm[1]), fmaxf(redm[2], redm[3]));
    float e0 = __expf(x.x - m), e1 = __expf(x.y - m);
    float e2 = __expf(x.z - m), e3 = __expf(x.w - m);
    float s = e0 + e1 + e2 + e3;
#pragma unroll
    for (int off = 32; off > 0; off >>= 1) s += __shfl_xor(s, off);
    if ((tid & 63) == 0) reds[tid >> 6] = s;
    __syncthreads();
    float inv = 1.0f / (reds[0] + reds[1] + reds[2] + reds[3]);
    x.x = e0 * inv; x.y = e1 * inv; x.z = e2 * inv; x.w = e3 * inv;
    *(float4*)&p[tid * 4] = x;
}

// ============ wv: attn[b,q,h,:] = sum_k P[b,h,q,k] * vs[b,k,h,:] ============
// grid (qt=16, bh=24), 64q x 64d tile, K-loop over 1024
__global__ __launch_bounds__(256) void wv_kernel(
    const float* __restrict__ scores, const float* __restrict__ vs,
    float* __restrict__ attn)
{
    const int qt = blockIdx.x, bh = blockIdx.y;
    const int b = bh / NH, h = bh % NH;
    __shared__ float Ps[64][65];  // [q][k]
    __shared__ float Vs[64][65];  // [k][d]
    const int tid = threadIdx.x;
    const int tx = tid & 15, ty = tid >> 4;
    float acc[4][4] = {};
    for (int kt = 0; kt < 16; ++kt) {
        __syncthreads();
#pragma unroll
        for (int l = 0; l < 16; ++l) {
            int idx = tid + l * 256;
            int m = idx >> 6, d = idx & 63;
            Ps[m][d] = scores[((size_t)bh * SEQ + qt * 64 + m) * SEQ + kt * 64 + d];
            Vs[m][d] = vs[(b * SEQ + kt * 64 + m) * DM + h * 64 + d];
        }
        __syncthreads();
#pragma unroll 8
        for (int kk = 0; kk < 64; ++kk) {
            float a[4], bb[4];
#pragma unroll
            for (int i = 0; i < 4; ++i) a[i] = Ps[ty * 4 + i][kk];
#pragma unroll
            for (int j = 0; j < 4; ++j) bb[j] = Vs[kk][tx * 4 + j];
#pragma unroll
            for (int i = 0; i < 4; ++i)
#pragma unroll
                for (int j = 0; j < 4; ++j) acc[i][j] += a[i] * bb[j];
        }
    }
#pragma unroll
    for (int i = 0; i < 4; ++i) {
        int q = qt * 64 + ty * 4 + i;
#pragma unroll
        for (int j = 0; j < 4; ++j) {
            int d = tx * 4 + j;
            attn[(b * SEQ + q) * DM + h * 64 + d] = acc[i][j];
        }
    }
}

// ============ w_rel: attn[b,q,h,:] += sum_k P[b,h,q,k] * relation_v[b,q,k,:] ============
// grid (q=1024, b=2); block does all 12 heads x 64 d for one (b,q)
__global__ __launch_bounds__(256) void wrel_kernel(
    const float* __restrict__ scores, const float* __restrict__ rv,
    float* __restrict__ attn)
{
    const int q = blockIdx.x, b = blockIdx.y;
    __shared__ float Ps[12][68];   // [h][k-chunk]; 68*4B = 272B = 16B-aligned rows
    __shared__ float RVs[64][65];  // [k][d]
    const int tid = threadIdx.x;
    const int d = tid & 63, hb = tid >> 6;  // heads hb, hb+4, hb+8
    const size_t rbase = ((size_t)(b * SEQ + q)) * SEQ * DK;
    float a0 = 0.f, a1 = 0.f, a2 = 0.f;
    for (int kt = 0; kt < 16; ++kt) {
        __syncthreads();
        if (tid < 192) {
            int h = tid >> 4, j = tid & 15;
            float4 t = *(const float4*)&scores[((size_t)(b * NH + h) * SEQ + q) * SEQ + kt * 64 + j * 4];
            *(float4*)&Ps[h][j * 4] = t;
        }
#pragma unroll
        for (int l = 0; l < 16; ++l) {
            int idx = tid + l * 256;
            int kk = idx >> 6, dd = idx & 63;
            RVs[kk][dd] = rv[rbase + (size_t)(kt * 64 + kk) * DK + dd];
        }
        __syncthreads();
#pragma unroll 8
        for (int kk = 0; kk < 64; ++kk) {
            float r = RVs[kk][d];
            a0 += Ps[hb][kk] * r;
            a1 += Ps[hb + 4][kk] * r;
            a2 += Ps[hb + 8][kk] * r;
        }
    }
    float* ap = attn + (size_t)(b * SEQ + q) * DM;
    ap[hb * 64 + d] += a0;
    ap[(hb + 4) * 64 + d] += a1;
    ap[(hb + 8) * 64 + d] += a2;
}

extern "C" void kernel_launch(void* const* d_in, const int* in_sizes, int n_in,
                              void* d_out, int out_size, void* d_ws, size_t ws_size,
                              hipStream_t stream)
{
    const float* queries = (const float*)d_in[0];
    const float* keys    = (const float*)d_in[1];
    const float* values  = (const float*)d_in[2];
    const float* rk      = (const float*)d_in[3];
    const float* rv      = (const float*)d_in[4];
    const float* Wq      = (const float*)d_in[5];
    const float* bq      = (const float*)d_in[6];
    const float* Wk      = (const float*)d_in[7];
    const float* bk      = (const float*)d_in[8];
    const float* Wv      = (const float*)d_in[9];
    const float* bv      = (const float*)d_in[10];
    const float* Wo      = (const float*)d_in[11];
    const float* bo      = (const float*)d_in[12];
    float* out = (float*)d_out;
    float* ws  = (float*)d_ws;

    float* qs    = ws + OFF_QS;
    float* ks    = ws + OFF_KS;
    float* vs    = ws + OFF_VS;
    float* attn  = ws + OFF_ATTN;
    float* sc    = ws + OFF_SC;

    dim3 gblk(256);
    dim3 ggrid(32, 12);
    // projections (q pre-scaled by 1/64: folds q*dk^-0.5 and /sqrt(dk))
    hipLaunchKernelGGL(gemm_bias_kernel, ggrid, gblk, 0, stream, queries, Wq, bq, qs, 1.0f / 64.0f);
    hipLaunchKernelGGL(gemm_bias_kernel, ggrid, gblk, 0, stream, keys,    Wk, bk, ks, 1.0f);
    hipLaunchKernelGGL(gemm_bias_kernel, ggrid, gblk, 0, stream, values,  Wv, bv, vs, 1.0f);
    // logits
    hipLaunchKernelGGL(qk_kernel,   dim3(16, 16, 24), gblk, 0, stream, qs, ks, sc);
    hipLaunchKernelGGL(relk_kernel, dim3(4, 1024, 2), gblk, 0, stream, qs, rk, sc);
    // softmax
    hipLaunchKernelGGL(softmax_kernel, dim3(24576), gblk, 0, stream, sc);
    // PV + relation-V
    hipLaunchKernelGGL(wv_kernel,   dim3(16, 24),   gblk, 0, stream, sc, vs, attn);
    hipLaunchKernelGGL(wrel_kernel, dim3(1024, 2),  gblk, 0, stream, sc, rv, attn);
    // output projection
    hipLaunchKernelGGL(gemm_bias_kernel, ggrid, gblk, 0, stream, attn, Wo, bo, out, 1.0f);
}